// Round 8
// baseline (193.047 us; speedup 1.0000x reference)
//
#include <hip/hip_runtime.h>
#include <hip/hip_bf16.h>
#include <math.h>

#define B_    32
#define C_    32768
#define ENC_  1024
#define VOCAB_ 100000
#define TOK_  256
#define HID_  512
#define HTILES_ (VOCAB_ / 16)   // 6250 half-tiles of 16 rows

typedef __attribute__((ext_vector_type(8))) short short8;
typedef __attribute__((ext_vector_type(4))) float f32x4;

__device__ __forceinline__ float gelu_exact(float x) {
    return 0.5f * x * (1.0f + erff(x * 0.70710678118654752f));
}

// Packed RNE f32x2 -> bf16x2 (v_cvt_pk_bf16_f32 on gfx950)
__device__ __forceinline__ unsigned pk2(float lo, float hi) {
    __hip_bfloat162 p = __float22bfloat162_rn(make_float2(lo, hi));
    unsigned r;
    __builtin_memcpy(&r, &p, 4);
    return r;
}

__device__ __forceinline__ short8 pack8(float4 a, float4 b) {
    union { short8 s8; unsigned u[4]; } r;
    r.u[0] = pk2(a.x, a.y);
    r.u[1] = pk2(a.z, a.w);
    r.u[2] = pk2(b.x, b.y);
    r.u[3] = pk2(b.z, b.w);
    return r.s8;
}

// K1: h[b][j] = gelu(enc[b] . W1[j] + b1[j])
__global__ __launch_bounds__(256) void k1_hidden(
    const float* __restrict__ enc, const float* __restrict__ W1,
    const float* __restrict__ b1, float* __restrict__ h)
{
    __shared__ float enc_lds[ENC_];
    const int b = blockIdx.y;
    const int tid = threadIdx.x;
    ((float4*)enc_lds)[tid] = ((const float4*)(enc + b * ENC_))[tid];
    __syncthreads();

    const int hw = tid >> 5, lane = tid & 31;
    const int jbase = blockIdx.x * 64 + hw * 8;
    const float4* enc4 = (const float4*)enc_lds;
    #pragma unroll
    for (int i = 0; i < 8; ++i) {
        const int j = jbase + i;
        const float4* wrow = (const float4*)(W1 + (size_t)j * ENC_);
        float acc = 0.f;
        #pragma unroll
        for (int t = 0; t < 8; ++t) {
            const int k4 = t * 32 + lane;
            float4 w = wrow[k4];
            float4 e = enc4[k4];
            acc += w.x * e.x + w.y * e.y + w.z * e.z + w.w * e.w;
        }
        #pragma unroll
        for (int m = 16; m >= 1; m >>= 1) acc += __shfl_xor(acc, m, 32);
        if (lane == 0) h[b * HID_ + j] = gelu_exact(acc + b1[j]);
    }
}

// K2: q[b][j] = h[b] . W2[j]
__global__ __launch_bounds__(256) void k2_q(
    const float* __restrict__ h, const float* __restrict__ W2,
    float* __restrict__ q)
{
    __shared__ float h_lds[HID_];
    const int b = blockIdx.y;
    const int tid = threadIdx.x;
    ((float2*)h_lds)[tid] = ((const float2*)(h + b * HID_))[tid];
    __syncthreads();

    const int hw = tid >> 5, lane = tid & 31;
    const int jbase = blockIdx.x * 64 + hw * 8;
    const float4* h4 = (const float4*)h_lds;
    #pragma unroll
    for (int i = 0; i < 8; ++i) {
        const int j = jbase + i;
        const float4* wrow = (const float4*)(W2 + (size_t)j * HID_);
        float acc = 0.f;
        #pragma unroll
        for (int t = 0; t < 4; ++t) {
            const int k4 = t * 32 + lane;
            float4 w = wrow[k4];
            float4 e = h4[k4];
            acc += w.x * e.x + w.y * e.y + w.z * e.z + w.w * e.w;
        }
        #pragma unroll
        for (int m = 16; m >= 1; m >>= 1) acc += __shfl_xor(acc, m, 32);
        if (lane == 0) q[b * TOK_ + j] = acc;
    }
}

// K3 v7: q_all[b][v] (bf16) = tok_emb[v] . q[b] — MFMA, deep load pipeline.
// vs v6: packed v_cvt_pk_bf16_f32 conversions (~4x less pack VALU) and
// __launch_bounds__(256,4) to pin >=4 waves/SIMD (<=128 VGPR; staging ~110).
// One 16-row half-tile per wave, all 16 A-loads staged upfront.
__global__ __launch_bounds__(256, 4) void k3_qall_mfma(
    const float* __restrict__ q, const float* __restrict__ tok_emb,
    __hip_bfloat16* __restrict__ q_all)
{
    __shared__ short8 q_lds[1024];            // 16 KB
    const int tid  = threadIdx.x;
    const int lane = tid & 63;
    const int hw   = tid >> 6;
    const int m  = lane & 15;
    const int kq = lane >> 4;                 // 0..3

    // B-fragment table: q_lds[(ks*2+n)*64+lane] = bf16x8 of q[n*16+m][ks*32+kq*8..+8]
    #pragma unroll
    for (int ks2 = 0; ks2 < 2; ++ks2) {
        const int ks = hw * 2 + ks2;
        #pragma unroll
        for (int n = 0; n < 2; ++n) {
            const float4* p = (const float4*)(q + (n * 16 + m) * TOK_ + ks * 32 + kq * 8);
            q_lds[(ks * 2 + n) * 64 + lane] = pack8(p[0], p[1]);
        }
    }
    __syncthreads();

    const int wave = blockIdx.x * 4 + hw;     // half-tile index
    if (wave >= HTILES_) return;
    const int v0 = wave * 16;

    const float* abase = tok_emb + (size_t)(v0 + m) * TOK_ + kq * 8;

    // Stage the whole half-tile: 16 dwordx4 loads in flight per wave.
    float4 st[16];
    #pragma unroll
    for (int ks = 0; ks < 8; ++ks) {
        st[ks * 2 + 0] = *(const float4*)(abase + ks * 32);
        st[ks * 2 + 1] = *(const float4*)(abase + ks * 32 + 4);
    }

    f32x4 acc0 = {0.f, 0.f, 0.f, 0.f};
    f32x4 acc1 = {0.f, 0.f, 0.f, 0.f};
    #pragma unroll
    for (int ks = 0; ks < 8; ++ks) {
        short8 af = pack8(st[ks * 2], st[ks * 2 + 1]);
        short8 b0 = q_lds[(ks * 2 + 0) * 64 + lane];
        short8 b1 = q_lds[(ks * 2 + 1) * 64 + lane];
        acc0 = __builtin_amdgcn_mfma_f32_16x16x32_bf16(af, b0, acc0, 0, 0, 0);
        acc1 = __builtin_amdgcn_mfma_f32_16x16x32_bf16(af, b1, acc1, 0, 0, 0);
    }

    // C/D: col = lane&15 -> b_local, row = kq*4+i -> v offset.
    // q_all[b][v]: b = n*16+m, v = v0 + kq*4 + i  (8B-aligned ushort4 store)
    union { ushort4 v; unsigned u[2]; } r0, r1;
    r0.u[0] = pk2(acc0[0], acc0[1]); r0.u[1] = pk2(acc0[2], acc0[3]);
    r1.u[0] = pk2(acc1[0], acc1[1]); r1.u[1] = pk2(acc1[2], acc1[3]);
    *(ushort4*)(q_all + (size_t)(m)      * VOCAB_ + v0 + kq * 4) = r0.v;
    *(ushort4*)(q_all + (size_t)(16 + m) * VOCAB_ + v0 + kq * 4) = r1.v;
}

// K4: out[b][c] = (float)q_all[b][cand[b][c]]
// XCD-pinned: blockIdx % 8 == b % 8; per-XCD window 4 rows x 200 KB = 800 KB,
// L2-resident.
__global__ __launch_bounds__(256) void k4_gather(
    const int* __restrict__ cand, const __hip_bfloat16* __restrict__ q_all,
    float* __restrict__ out)
{
    const int b     = blockIdx.x & 31;
    const int chunk = blockIdx.x >> 5;
    const int c0 = chunk * 1024 + threadIdx.x * 4;
    const int4 t = *(const int4*)(cand + (size_t)b * C_ + c0);
    const __hip_bfloat16* row = q_all + (size_t)b * VOCAB_;
    float4 r;
    r.x = __bfloat162float(row[t.x]);
    r.y = __bfloat162float(row[t.y]);
    r.z = __bfloat162float(row[t.z]);
    r.w = __bfloat162float(row[t.w]);
    *(float4*)(out + (size_t)b * C_ + c0) = r;
}

extern "C" void kernel_launch(void* const* d_in, const int* in_sizes, int n_in,
                              void* d_out, int out_size, void* d_ws, size_t ws_size,
                              hipStream_t stream) {
    const float* enc     = (const float*)d_in[0];   // (32, 1024)
    const int*   cand    = (const int*)  d_in[1];   // (32, 32768)
    const float* tok_emb = (const float*)d_in[2];   // (100000, 256)
    const float* W1      = (const float*)d_in[3];   // (512, 1024)
    const float* b1      = (const float*)d_in[4];   // (512,)
    const float* W2      = (const float*)d_in[5];   // (256, 512)
    float* out = (float*)d_out;                     // (32, 32768)

    float* h = (float*)d_ws;                        // 32*512 floats
    float* q = h + B_ * HID_;                       // 32*256 floats
    __hip_bfloat16* q_all = (__hip_bfloat16*)(q + B_ * TOK_);  // 32 x 100000 bf16 (6.4 MB)

    k1_hidden<<<dim3(8, 32), 256, 0, stream>>>(enc, W1, b1, h);
    k2_q     <<<dim3(4, 32), 256, 0, stream>>>(h, W2, q);

    const int blocks3 = (HTILES_ + 3) / 4;          // 1563
    k3_qall_mfma<<<blocks3, 256, 0, stream>>>(q, tok_emb, q_all);

    k4_gather<<<32 * 32, 256, 0, stream>>>(cand, q_all, out);
}

// Round 9
// 190.798 us; speedup vs baseline: 1.0118x; 1.0118x over previous
//
#include <hip/hip_runtime.h>
#include <hip/hip_bf16.h>
#include <math.h>

#define B_    32
#define C_    32768
#define ENC_  1024
#define VOCAB_ 100000
#define TOK_  256
#define HID_  512

typedef __attribute__((ext_vector_type(8))) short short8;
typedef __attribute__((ext_vector_type(4))) float f32x4;

__device__ __forceinline__ float gelu_exact(float x) {
    return 0.5f * x * (1.0f + erff(x * 0.70710678118654752f));
}

// Packed RNE f32x2 -> bf16x2 (v_cvt_pk_bf16_f32 on gfx950)
__device__ __forceinline__ unsigned pk2(float lo, float hi) {
    __hip_bfloat162 p = __float22bfloat162_rn(make_float2(lo, hi));
    unsigned r;
    __builtin_memcpy(&r, &p, 4);
    return r;
}

__device__ __forceinline__ short8 pack8(float4 a, float4 b) {
    union { short8 s8; unsigned u[4]; } r;
    r.u[0] = pk2(a.x, a.y);
    r.u[1] = pk2(a.z, a.w);
    r.u[2] = pk2(b.x, b.y);
    r.u[3] = pk2(b.z, b.w);
    return r.s8;
}

// K1: h[b][j] = gelu(enc[b] . W1[j] + b1[j])
__global__ __launch_bounds__(256) void k1_hidden(
    const float* __restrict__ enc, const float* __restrict__ W1,
    const float* __restrict__ b1, float* __restrict__ h)
{
    __shared__ float enc_lds[ENC_];
    const int b = blockIdx.y;
    const int tid = threadIdx.x;
    ((float4*)enc_lds)[tid] = ((const float4*)(enc + b * ENC_))[tid];
    __syncthreads();

    const int hw = tid >> 5, lane = tid & 31;
    const int jbase = blockIdx.x * 64 + hw * 8;
    const float4* enc4 = (const float4*)enc_lds;
    #pragma unroll
    for (int i = 0; i < 8; ++i) {
        const int j = jbase + i;
        const float4* wrow = (const float4*)(W1 + (size_t)j * ENC_);
        float acc = 0.f;
        #pragma unroll
        for (int t = 0; t < 8; ++t) {
            const int k4 = t * 32 + lane;
            float4 w = wrow[k4];
            float4 e = enc4[k4];
            acc += w.x * e.x + w.y * e.y + w.z * e.z + w.w * e.w;
        }
        #pragma unroll
        for (int m = 16; m >= 1; m >>= 1) acc += __shfl_xor(acc, m, 32);
        if (lane == 0) h[b * HID_ + j] = gelu_exact(acc + b1[j]);
    }
}

// K2: q[b][j] = h[b] . W2[j]
__global__ __launch_bounds__(256) void k2_q(
    const float* __restrict__ h, const float* __restrict__ W2,
    float* __restrict__ q)
{
    __shared__ float h_lds[HID_];
    const int b = blockIdx.y;
    const int tid = threadIdx.x;
    ((float2*)h_lds)[tid] = ((const float2*)(h + b * HID_))[tid];
    __syncthreads();

    const int hw = tid >> 5, lane = tid & 31;
    const int jbase = blockIdx.x * 64 + hw * 8;
    const float4* h4 = (const float4*)h_lds;
    #pragma unroll
    for (int i = 0; i < 8; ++i) {
        const int j = jbase + i;
        const float4* wrow = (const float4*)(W2 + (size_t)j * HID_);
        float acc = 0.f;
        #pragma unroll
        for (int t = 0; t < 4; ++t) {
            const int k4 = t * 32 + lane;
            float4 w = wrow[k4];
            float4 e = h4[k4];
            acc += w.x * e.x + w.y * e.y + w.z * e.z + w.w * e.w;
        }
        #pragma unroll
        for (int m = 16; m >= 1; m >>= 1) acc += __shfl_xor(acc, m, 32);
        if (lane == 0) q[b * TOK_ + j] = acc;
    }
}

// K3 v9: q_all[b][v] (bf16) = tok_emb[v] . q[b] — LDS-staged MFMA GEMM.
// vs v7: global loads are now COPY-SHAPED (wave reads 1 KiB lane-contiguous
// per instruction, 100% line utilization) instead of fragment-direct
// (16 rows x 16B per instr, 50% line density, 2x line-request amplification).
// Block stages 64 rows fp32->bf16 into padded LDS (row stride 264 bf16),
// one barrier, each of 4 waves MFMAs a 16-row group from LDS.
__global__ __launch_bounds__(256, 3) void k3_qall_mfma(
    const float* __restrict__ q, const float* __restrict__ tok_emb,
    __hip_bfloat16* __restrict__ q_all)
{
    __shared__ unsigned short a_lds[64 * 264];   // 33792 B, +8 bf16 row pad
    __shared__ short8 q_lds[1024];               // 16 KB B-table
    const int tid  = threadIdx.x;
    const int lane = tid & 63;
    const int hw   = tid >> 6;
    const int m  = lane & 15;
    const int kq = lane >> 4;                    // 0..3

    // B-table: q_lds[(ks*2+n)*64+lane] = bf16x8 of q[n*16+m][ks*32+kq*8..+8]
    #pragma unroll
    for (int ks2 = 0; ks2 < 2; ++ks2) {
        const int ks = hw * 2 + ks2;
        #pragma unroll
        for (int n = 0; n < 2; ++n) {
            const float4* p = (const float4*)(q + (n * 16 + m) * TOK_ + ks * 32 + kq * 8);
            q_lds[(ks * 2 + n) * 64 + lane] = pack8(p[0], p[1]);
        }
    }

    const int vb = blockIdx.x * 64;              // block row base

    // Stage: wave hw, iter i -> row i*4+hw, lane = float4 column.
    // Each instr: 64 lanes x 16B = one full 1 KiB row, dense. All 16 issued
    // upfront (16 KB in flight per wave).
    float4 stg[16];
    #pragma unroll
    for (int i = 0; i < 16; ++i) {
        const int vr = min(vb + i * 4 + hw, VOCAB_ - 1);   // tail clamp
        stg[i] = *(const float4*)(tok_emb + (size_t)vr * TOK_ + lane * 4);
    }
    #pragma unroll
    for (int i = 0; i < 16; ++i) {
        const int r = i * 4 + hw;
        uint2 w;
        w.x = pk2(stg[i].x, stg[i].y);
        w.y = pk2(stg[i].z, stg[i].w);
        *(uint2*)(&a_lds[r * 264 + lane * 4]) = w;         // 8B, 8B-aligned
    }
    __syncthreads();

    const int v0 = vb + hw * 16;
    if (v0 < VOCAB_) {                           // VOCAB_ % 16 == 0
        const int rloc = hw * 16 + m;
        f32x4 acc0 = {0.f, 0.f, 0.f, 0.f};
        f32x4 acc1 = {0.f, 0.f, 0.f, 0.f};
        #pragma unroll
        for (int ks = 0; ks < 8; ++ks) {
            // 16B-aligned ds_read_b128; bank-quad = (m + kq + 4*(ks&1)) & 7,
            // 8 lanes per quad, even spread.
            short8 af = *(const short8*)(&a_lds[rloc * 264 + ks * 32 + kq * 8]);
            short8 b0 = q_lds[(ks * 2 + 0) * 64 + lane];
            short8 b1 = q_lds[(ks * 2 + 1) * 64 + lane];
            acc0 = __builtin_amdgcn_mfma_f32_16x16x32_bf16(af, b0, acc0, 0, 0, 0);
            acc1 = __builtin_amdgcn_mfma_f32_16x16x32_bf16(af, b1, acc1, 0, 0, 0);
        }

        // q_all[b][v]: b = n*16+m, v = v0 + kq*4 + i  (8B-aligned ushort4)
        union { ushort4 v; unsigned u[2]; } r0, r1;
        r0.u[0] = pk2(acc0[0], acc0[1]); r0.u[1] = pk2(acc0[2], acc0[3]);
        r1.u[0] = pk2(acc1[0], acc1[1]); r1.u[1] = pk2(acc1[2], acc1[3]);
        *(ushort4*)(q_all + (size_t)(m)      * VOCAB_ + v0 + kq * 4) = r0.v;
        *(ushort4*)(q_all + (size_t)(16 + m) * VOCAB_ + v0 + kq * 4) = r1.v;
    }
}

// K4: out[b][c] = (float)q_all[b][cand[b][c]]
// XCD-pinned: blockIdx % 8 == b % 8; per-XCD window 4 rows x 200 KB = 800 KB,
// L2-resident.
__global__ __launch_bounds__(256) void k4_gather(
    const int* __restrict__ cand, const __hip_bfloat16* __restrict__ q_all,
    float* __restrict__ out)
{
    const int b     = blockIdx.x & 31;
    const int chunk = blockIdx.x >> 5;
    const int c0 = chunk * 1024 + threadIdx.x * 4;
    const int4 t = *(const int4*)(cand + (size_t)b * C_ + c0);
    const __hip_bfloat16* row = q_all + (size_t)b * VOCAB_;
    float4 r;
    r.x = __bfloat162float(row[t.x]);
    r.y = __bfloat162float(row[t.y]);
    r.z = __bfloat162float(row[t.z]);
    r.w = __bfloat162float(row[t.w]);
    *(float4*)(out + (size_t)b * C_ + c0) = r;
}

extern "C" void kernel_launch(void* const* d_in, const int* in_sizes, int n_in,
                              void* d_out, int out_size, void* d_ws, size_t ws_size,
                              hipStream_t stream) {
    const float* enc     = (const float*)d_in[0];   // (32, 1024)
    const int*   cand    = (const int*)  d_in[1];   // (32, 32768)
    const float* tok_emb = (const float*)d_in[2];   // (100000, 256)
    const float* W1      = (const float*)d_in[3];   // (512, 1024)
    const float* b1      = (const float*)d_in[4];   // (512,)
    const float* W2      = (const float*)d_in[5];   // (256, 512)
    float* out = (float*)d_out;                     // (32, 32768)

    float* h = (float*)d_ws;                        // 32*512 floats
    float* q = h + B_ * HID_;                       // 32*256 floats
    __hip_bfloat16* q_all = (__hip_bfloat16*)(q + B_ * TOK_);  // 32 x 100000 bf16 (6.4 MB)

    k1_hidden<<<dim3(8, 32), 256, 0, stream>>>(enc, W1, b1, h);
    k2_q     <<<dim3(4, 32), 256, 0, stream>>>(h, W2, q);

    const int blocks3 = (VOCAB_ + 63) / 64;         // 1563 (64 rows per block)
    k3_qall_mfma<<<blocks3, 256, 0, stream>>>(q, tok_emb, q_all);

    k4_gather<<<32 * 32, 256, 0, stream>>>(cand, q_all, out);
}